// Round 12
// baseline (44.436 us; speedup 1.0000x reference)
//
#include <hip/hip_runtime.h>
#include <cstdint>

// DeepSeek-V3 MoE routing, MI355X. T=131072, E=256, G=8x32, topk_group=4, top_k=8.
// R12: TWO tokens per wave, INTERLEAVED (not sequential as failed R9):
//   - both tokens' sigmoid/group/key phases in one straight-line region
//   - ONE combined radix loop (8 ballots/iter, exit when both tokens settle):
//     t1's ballots fill t0's v_cmp->SALU->cselect latency bubbles
//   - single lgkmcnt barrier after BOTH compactions
//   Theory: R7/R10/R11 evidence says serial-chain latency (not issue count)
//   now binds; interleaving doubles issue density on the critical chains.

constexpr int TOPK_GROUP  = 4;
constexpr int TOP_K       = 8;
constexpr float ROUTED_SCALING = 2.5f;
constexpr unsigned KEY_OFF = 0x3F000000u;   // bits(0.5f); low 16 bits zero

// DPP controls: quad_perm xor1/xor2, row_half_mirror (pairs within 8), row_mirror.
#define DPP_XOR1 0xB1
#define DPP_XOR2 0x4E
#define DPP_HM   0x141
#define DPP_M    0x140

template <int CTRL>
static __device__ __forceinline__ float dpp_f32(float x) {
  return __int_as_float(__builtin_amdgcn_mov_dpp(__float_as_int(x), CTRL, 0xF, 0xF, true));
}
template <int CTRL>
static __device__ __forceinline__ unsigned dpp_u32(unsigned x) {
  return (unsigned)__builtin_amdgcn_mov_dpp((int)x, CTRL, 0xF, 0xF, true);
}

static __device__ __forceinline__ int mbcnt64(unsigned long long m) {
  return __builtin_amdgcn_mbcnt_hi((unsigned)(m >> 32),
         __builtin_amdgcn_mbcnt_lo((unsigned)m, 0));
}

static __device__ __forceinline__ unsigned umax2(unsigned x, unsigned y) {
  return x > y ? x : y;
}

static __device__ __forceinline__ float fast_sig(float x) {
  // 1/(1 + 2^(-x*log2e)); raw v_rcp (<=1 ulp, validated R9-R11)
  return __builtin_amdgcn_rcpf(1.0f + __builtin_amdgcn_exp2f(x * -1.44269504f));
}

// Selection tail for one token: masks, rare tie slow path, LDS compaction.
static __device__ __forceinline__ void finish_select(
    const unsigned k0, const unsigned k1, const unsigned k2, const unsigned k3,
    const unsigned tf, const int ebase,
    const float sig0, const float sig1, const float sig2, const float sig3,
    float2* __restrict__ tb) {
  bool sel0 = k0 >= tf, sel1 = k1 >= tf, sel2 = k2 >= tf, sel3 = k3 >= tf;
  unsigned long long sm0 = __ballot(sel0), sm1 = __ballot(sel1),
                     sm2 = __ballot(sel2), sm3 = __ballot(sel3);
  const int cnt = __popcll(sm0) + __popcll(sm1) + __popcll(sm2) + __popcll(sm3);

  if (cnt > TOP_K) {   // wave-uniform slow path: ties within the 2^16 bucket
    const unsigned tg = tf + 0x10000u;   // KEY_OFF low16==0 -> bucket math exact
    const bool c0 = sel0 && (k0 < tg);
    const bool c1 = sel1 && (k1 < tg);
    const bool c2 = sel2 && (k2 < tg);
    const bool c3 = sel3 && (k3 < tg);
    const int nc = __popcll(__ballot(c0)) + __popcll(__ballot(c1))
                 + __popcll(__ballot(c2)) + __popcll(__ballot(c3));
    const int need2 = TOP_K - (cnt - nc);   // 1..8 to admit
    sel0 = sel0 && !c0; sel1 = sel1 && !c1;
    sel2 = sel2 && !c2; sel3 = sel3 && !c3;
    unsigned p0 = c0 ? (((k0 & 0xFFFFu) << 16) | (0xFFFFu - (unsigned)(ebase + 0))) : 0u;
    unsigned p1 = c1 ? (((k1 & 0xFFFFu) << 16) | (0xFFFFu - (unsigned)(ebase + 1))) : 0u;
    unsigned p2 = c2 ? (((k2 & 0xFFFFu) << 16) | (0xFFFFu - (unsigned)(ebase + 2))) : 0u;
    unsigned p3 = c3 ? (((k3 & 0xFFFFu) << 16) | (0xFFFFu - (unsigned)(ebase + 3))) : 0u;
    for (int r = 0; r < need2; ++r) {       // wave-uniform trips (exp. 1)
      unsigned mm = umax2(umax2(p0, p1), umax2(p2, p3));
      mm = umax2(mm, dpp_u32<DPP_XOR1>(mm));
      mm = umax2(mm, dpp_u32<DPP_XOR2>(mm));
      mm = umax2(mm, dpp_u32<DPP_HM>(mm));               // uniform within 8
      mm = umax2(mm, dpp_u32<DPP_M>(mm));                // uniform within 16
      mm = umax2(mm, (unsigned)__shfl_xor((int)mm, 16));
      mm = umax2(mm, (unsigned)__shfl_xor((int)mm, 32)); // wave-uniform
      const bool w0 = (p0 == mm), w1 = (p1 == mm), w2 = (p2 == mm), w3 = (p3 == mm);
      sel0 = sel0 || w0; sel1 = sel1 || w1;
      sel2 = sel2 || w2; sel3 = sel3 || w3;
      p0 = w0 ? 0u : p0; p1 = w1 ? 0u : p1;
      p2 = w2 ? 0u : p2; p3 = w3 ? 0u : p3;
    }
    sm0 = __ballot(sel0); sm1 = __ballot(sel1);
    sm2 = __ballot(sel2); sm3 = __ballot(sel3);
  }

  // branchless compaction: selected -> slot 0..7, else trash slot 8..11
  const int sbelow = mbcnt64(sm0) + mbcnt64(sm1) + mbcnt64(sm2) + mbcnt64(sm3);
  const int slot0 = sbelow;
  const int slot1 = slot0 + (int)sel0;
  const int slot2 = slot1 + (int)sel1;
  const int slot3 = slot2 + (int)sel2;
  tb[sel0 ? slot0 : 8]  = make_float2(__int_as_float(ebase + 0), sig0);
  tb[sel1 ? slot1 : 9]  = make_float2(__int_as_float(ebase + 1), sig1);
  tb[sel2 ? slot2 : 10] = make_float2(__int_as_float(ebase + 2), sig2);
  tb[sel3 ? slot3 : 11] = make_float2(__int_as_float(ebase + 3), sig3);
}

// Readback + renormalize + rank + fused store for one token.
static __device__ __forceinline__ void readback_store(
    const float2* __restrict__ tb, const int token, const int lane,
    float* __restrict__ out_idx, float* __restrict__ out_val) {
  const int l8 = lane & 7;
  const float2 w  = tb[l8];
  const float2 wo = tb[lane >> 3];
  const float wsig = w.y;
  float ssum = wsig;
  ssum += dpp_f32<DPP_XOR1>(ssum);
  ssum += dpp_f32<DPP_XOR2>(ssum);
  ssum += dpp_f32<DPP_HM>(ssum);
  const float inv = __builtin_amdgcn_rcpf(ssum);   // <=1 ulp; ssum >= ~1e-3
  const float val = wsig * inv * ROUTED_SCALING;   // identical op order both uses
  const float v_o = wo.y * inv * ROUTED_SCALING;   // bit-identical to owner's val
  const int widx_i = __float_as_int(w.x);
  const int i_o_i  = __float_as_int(wo.x);
  const unsigned long long rm =
      __ballot((val > v_o) || (val == v_o && widx_i < i_o_i));
  const int rank = __popc((unsigned)(rm >> (l8 << 3)) & 0xFFu);
  if (lane < 16) {
    float* base = (lane < 8) ? out_idx : out_val;
    base[token * TOP_K + rank] = (lane < 8) ? (float)widx_i : val;
  }
}

__global__ __launch_bounds__(256) void moe_route_kernel(
    const float* __restrict__ logits,   // [T, 256]
    const float* __restrict__ bias,     // [256]
    float* __restrict__ out_idx,        // [T, 8] indices as float
    float* __restrict__ out_val,        // [T, 8]
    int n_tokens) {
  const int lane = threadIdx.x & 63;
  const int wid  = threadIdx.x >> 6;
  const int tA = blockIdx.x * 8 + wid * 2;   // grid exact: no bounds guard
  const int tB = tA + 1;
  __shared__ float2 buf[4][2][16];           // per-wave, per-token slabs (+pad)

  // ---- both tokens' loads issue up front ----
  const float4* lp = reinterpret_cast<const float4*>(logits) + tA * 64 + lane;
  const float4 lvA = lp[0];
  const float4 lvB = lp[64];
  const float4 bv  = reinterpret_cast<const float4*>(bias)[lane];

  // ---- sigmoids, both tokens (independent chains, trans pipe) ----
  const float sigA0 = fast_sig(lvA.x), sigA1 = fast_sig(lvA.y);
  const float sigA2 = fast_sig(lvA.z), sigA3 = fast_sig(lvA.w);
  const float sigB0 = fast_sig(lvB.x), sigB1 = fast_sig(lvB.y);
  const float sigB2 = fast_sig(lvB.z), sigB3 = fast_sig(lvB.w);
  const float swbA0 = sigA0 + bv.x, swbA1 = sigA1 + bv.y;
  const float swbA2 = sigA2 + bv.z, swbA3 = sigA3 + bv.w;
  const float swbB0 = sigB0 + bv.x, swbB1 = sigB1 + bv.y;
  const float swbB2 = sigB2 + bv.z, swbB3 = sigB3 + bv.w;

  // ---- group scores, both tokens, DPP merges interleaved ----
  float m1A, m2A, m1B, m2B;
  {
    const float h1 = fmaxf(swbA0, swbA1), l1 = fminf(swbA0, swbA1);
    const float h2 = fmaxf(swbA2, swbA3), l2 = fminf(swbA2, swbA3);
    m1A = fmaxf(h1, h2);
    m2A = fmaxf(fminf(h1, h2), fmaxf(l1, l2));
  }
  {
    const float h1 = fmaxf(swbB0, swbB1), l1 = fminf(swbB0, swbB1);
    const float h2 = fmaxf(swbB2, swbB3), l2 = fminf(swbB2, swbB3);
    m1B = fmaxf(h1, h2);
    m2B = fmaxf(fminf(h1, h2), fmaxf(l1, l2));
  }
#define MERGE_LEV2(CTRL)                                           \
  {                                                                \
    const float oA1 = dpp_f32<CTRL>(m1A);                          \
    const float oA2 = dpp_f32<CTRL>(m2A);                          \
    const float oB1 = dpp_f32<CTRL>(m1B);                          \
    const float oB2 = dpp_f32<CTRL>(m2B);                          \
    const float nA1 = fmaxf(m1A, oA1);                             \
    const float nA2 = fmaxf(fminf(m1A, oA1), fmaxf(m2A, oA2));     \
    const float nB1 = fmaxf(m1B, oB1);                             \
    const float nB2 = fmaxf(fminf(m1B, oB1), fmaxf(m2B, oB2));     \
    m1A = nA1; m2A = nA2; m1B = nB1; m2B = nB2;                    \
  }
  MERGE_LEV2(DPP_XOR1)
  MERGE_LEV2(DPP_XOR2)
  MERGE_LEV2(DPP_HM)
#undef MERGE_LEV2
  const float gscoreA = m1A + m2A;
  const float gscoreB = m1B + m2B;

  // ---- group rank, both tokens ----
  const int g = lane >> 3;
  const int a = lane & 7;
  const float gsoA = __shfl(gscoreA, a << 3);
  const float gsoB = __shfl(gscoreB, a << 3);
  const unsigned long long gmA =
      __ballot((gsoA > gscoreA) || (gsoA == gscoreA && a < g));
  const unsigned long long gmB =
      __ballot((gsoB > gscoreB) || (gsoB == gscoreB && a < g));
  const bool gselA = __popc((unsigned)(gmA >> (g << 3)) & 0xFFu) < TOPK_GROUP;
  const bool gselB = __popc((unsigned)(gmB >> (g << 3)) & 0xFFu) < TOPK_GROUP;

  // ---- float-domain biased keys (< 2^25), both tokens ----
  const int ebase = lane << 2;
  const unsigned kA0 = gselA ? ((unsigned)__float_as_int(fmaxf(swbA0, 0.5f)) - KEY_OFF) : 0u;
  const unsigned kA1 = gselA ? ((unsigned)__float_as_int(fmaxf(swbA1, 0.5f)) - KEY_OFF) : 0u;
  const unsigned kA2 = gselA ? ((unsigned)__float_as_int(fmaxf(swbA2, 0.5f)) - KEY_OFF) : 0u;
  const unsigned kA3 = gselA ? ((unsigned)__float_as_int(fmaxf(swbA3, 0.5f)) - KEY_OFF) : 0u;
  const unsigned kB0 = gselB ? ((unsigned)__float_as_int(fmaxf(swbB0, 0.5f)) - KEY_OFF) : 0u;
  const unsigned kB1 = gselB ? ((unsigned)__float_as_int(fmaxf(swbB1, 0.5f)) - KEY_OFF) : 0u;
  const unsigned kB2 = gselB ? ((unsigned)__float_as_int(fmaxf(swbB2, 0.5f)) - KEY_OFF) : 0u;
  const unsigned kB3 = gselB ? ((unsigned)__float_as_int(fmaxf(swbB3, 0.5f)) - KEY_OFF) : 0u;

  // ---- combined radix select, bits [24:16]: 8 independent ballots per iter
  //      (tokenB's fill tokenA's SALU bubbles); exit when BOTH settled.
  //      Post-done refinement is set-preserving (count>=8 invariant). ----
  unsigned tfA = 0u, tfB = 0u;
  bool doneA = false, doneB = false;
  for (int bit = 24; bit >= 16; --bit) {
    const unsigned candA = tfA | (1u << bit);
    const unsigned candB = tfB | (1u << bit);
    const int cA = __popcll(__ballot(kA0 >= candA)) + __popcll(__ballot(kA1 >= candA))
                 + __popcll(__ballot(kA2 >= candA)) + __popcll(__ballot(kA3 >= candA));
    const int cB = __popcll(__ballot(kB0 >= candB)) + __popcll(__ballot(kB1 >= candB))
                 + __popcll(__ballot(kB2 >= candB)) + __popcll(__ballot(kB3 >= candB));
    tfA = (cA >= TOP_K) ? candA : tfA;
    tfB = (cB >= TOP_K) ? candB : tfB;
    doneA = doneA || (cA == TOP_K);
    doneB = doneB || (cB == TOP_K);
    if (doneA && doneB) break;
  }

  // ---- per-token tails: masks, rare tie resolution, LDS compaction ----
  finish_select(kA0, kA1, kA2, kA3, tfA, ebase, sigA0, sigA1, sigA2, sigA3, buf[wid][0]);
  finish_select(kB0, kB1, kB2, kB3, tfB, ebase, sigB0, sigB1, sigB2, sigB3, buf[wid][1]);
  asm volatile("s_waitcnt lgkmcnt(0)" ::: "memory");  // ONE barrier for both

  // ---- readback + store, both tokens ----
  readback_store(buf[wid][0], tA, lane, out_idx, out_val);
  readback_store(buf[wid][1], tB, lane, out_idx, out_val);
}

extern "C" void kernel_launch(void* const* d_in, const int* in_sizes, int n_in,
                              void* d_out, int out_size, void* d_ws, size_t ws_size,
                              hipStream_t stream) {
  const float* logits = (const float*)d_in[0];
  const float* bias   = (const float*)d_in[1];
  float* out = (float*)d_out;

  const int n_tokens = in_sizes[0] / 256;
  float* out_idx = out;
  float* out_val = out + (size_t)n_tokens * TOP_K;

  const int blocks = n_tokens / 8;   // 4 waves/block, 2 tokens/wave
  moe_route_kernel<<<blocks, 256, 0, stream>>>(logits, bias, out_idx, out_val, n_tokens);
}

// Round 13
// 41.101 us; speedup vs baseline: 1.0811x; 1.0811x over previous
//
#include <hip/hip_runtime.h>
#include <cstdint>

// DeepSeek-V3 MoE routing, MI355X. T=131072, E=256, G=8x32, topk_group=4, top_k=8.
// One wave per token; lane i owns experts 4i..4i+3.
// R13 = exact revert to R10 (best measured: 40.9us). Evidence across R5-R12:
//   VALU-issue-bound (~93% VALUBusy); critical-chain cuts win (R10 radix domain
//   shrink + early exit), off-chain diets neutral (R6/R11), added work regresses
//   (R7 SALU->VALU move, R9/R12 two-token variants). This is the plateau kernel.

constexpr int TOPK_GROUP  = 4;
constexpr int TOP_K       = 8;
constexpr float ROUTED_SCALING = 2.5f;
constexpr unsigned KEY_BIAS = 0xBF000000u;   // sortable(0.5f); low 16 bits zero

// DPP controls: quad_perm xor1/xor2, row_half_mirror (pairs within 8), row_mirror.
#define DPP_XOR1 0xB1
#define DPP_XOR2 0x4E
#define DPP_HM   0x141
#define DPP_M    0x140

template <int CTRL>
static __device__ __forceinline__ float dpp_f32(float x) {
  return __int_as_float(__builtin_amdgcn_mov_dpp(__float_as_int(x), CTRL, 0xF, 0xF, true));
}
template <int CTRL>
static __device__ __forceinline__ unsigned dpp_u32(unsigned x) {
  return (unsigned)__builtin_amdgcn_mov_dpp((int)x, CTRL, 0xF, 0xF, true);
}

static __device__ __forceinline__ unsigned sortable_f32(float f) {
  const int u = __float_as_int(f);
  const int m = (u >> 31) | 0x80000000;
  return (unsigned)(u ^ m);
}

static __device__ __forceinline__ int mbcnt64(unsigned long long m) {
  return __builtin_amdgcn_mbcnt_hi((unsigned)(m >> 32),
         __builtin_amdgcn_mbcnt_lo((unsigned)m, 0));
}

static __device__ __forceinline__ unsigned umax2(unsigned x, unsigned y) {
  return x > y ? x : y;
}

__global__ __launch_bounds__(256) void moe_route_kernel(
    const float* __restrict__ logits,   // [T, 256]
    const float* __restrict__ bias,     // [256]
    float* __restrict__ out_idx,        // [T, 8] indices as float
    float* __restrict__ out_val,        // [T, 8]
    int n_tokens) {
  const int lane = threadIdx.x & 63;
  const int wid  = threadIdx.x >> 6;
  const int token = blockIdx.x * 4 + wid;   // grid exact: no bounds guard
  __shared__ float2 buf[4][TOP_K];          // per-wave 8 winner (idx_bits, sig)

  // ---- loads (32-bit indexing) ----
  const float4 lv = reinterpret_cast<const float4*>(logits)[token * 64 + lane];
  const float4 bv = reinterpret_cast<const float4*>(bias)[lane];

  // ---- direct-exp2 sigmoid: 1/(1 + 2^(-x*log2e)); raw v_rcp (<=1 ulp) ----
  const float sig0 = __builtin_amdgcn_rcpf(1.0f + __builtin_amdgcn_exp2f(lv.x * -1.44269504f));
  const float sig1 = __builtin_amdgcn_rcpf(1.0f + __builtin_amdgcn_exp2f(lv.y * -1.44269504f));
  const float sig2 = __builtin_amdgcn_rcpf(1.0f + __builtin_amdgcn_exp2f(lv.z * -1.44269504f));
  const float sig3 = __builtin_amdgcn_rcpf(1.0f + __builtin_amdgcn_exp2f(lv.w * -1.44269504f));
  const float swb0 = sig0 + bv.x;
  const float swb1 = sig1 + bv.y;
  const float swb2 = sig2 + bv.z;
  const float swb3 = sig3 + bv.w;

  // ---- group score: top-2 sum within each group (lanes 8g..8g+7), DPP merge ----
  const float h1 = fmaxf(swb0, swb1), l1 = fminf(swb0, swb1);
  const float h2 = fmaxf(swb2, swb3), l2 = fminf(swb2, swb3);
  float m1 = fmaxf(h1, h2);
  float m2 = fmaxf(fminf(h1, h2), fmaxf(l1, l2));
#define MERGE_LEV(CTRL)                                            \
  {                                                                \
    const float o1 = dpp_f32<CTRL>(m1);                            \
    const float o2 = dpp_f32<CTRL>(m2);                            \
    const float nm1 = fmaxf(m1, o1);                               \
    const float nm2 = fmaxf(fminf(m1, o1), fmaxf(m2, o2));         \
    m1 = nm1; m2 = nm2;                                            \
  }
  MERGE_LEV(DPP_XOR1)
  MERGE_LEV(DPP_XOR2)
  MERGE_LEV(DPP_HM)
#undef MERGE_LEV
  const float gscore = m1 + m2;

  // ---- group rank via one pairwise ballot ----
  const int g = lane >> 3;
  const int a = lane & 7;
  const float gs_o = __shfl(gscore, a << 3);
  const unsigned long long gm =
      __ballot((gs_o > gscore) || (gs_o == gscore && a < g));
  const int grank = __popc((unsigned)(gm >> (g << 3)) & 0xFFu);
  const bool gsel = grank < TOPK_GROUP;

  // ---- biased sortable keys (< 2^25); non-selected groups -> 0 ----
  const int ebase = lane << 2;
  const unsigned k0 = gsel ? (umax2(sortable_f32(swb0), KEY_BIAS) - KEY_BIAS) : 0u;
  const unsigned k1 = gsel ? (umax2(sortable_f32(swb1), KEY_BIAS) - KEY_BIAS) : 0u;
  const unsigned k2 = gsel ? (umax2(sortable_f32(swb2), KEY_BIAS) - KEY_BIAS) : 0u;
  const unsigned k3 = gsel ? (umax2(sortable_f32(swb3), KEY_BIAS) - KEY_BIAS) : 0u;

  // ---- radix select on bits [24:16]; early exit when count hits exactly 8
  //      (then {k >= cand} IS the top-8). Counting/update on SALU. ----
  unsigned tf = 0u;
  for (int bit = 24; bit >= 16; --bit) {
    const unsigned cand = tf | (1u << bit);
    const int c = __popcll(__ballot(k0 >= cand)) + __popcll(__ballot(k1 >= cand))
                + __popcll(__ballot(k2 >= cand)) + __popcll(__ballot(k3 >= cand));
    if (c >= TOP_K) {
      tf = cand;
      if (c == TOP_K) break;   // exact: remaining bits can't change the set
    }
  }

  bool sel0 = k0 >= tf, sel1 = k1 >= tf, sel2 = k2 >= tf, sel3 = k3 >= tf;
  unsigned long long sm0 = __ballot(sel0), sm1 = __ballot(sel1),
                     sm2 = __ballot(sel2), sm3 = __ballot(sel3);
  const int cnt = __popcll(sm0) + __popcll(sm1) + __popcll(sm2) + __popcll(sm3);

  if (cnt > TOP_K) {   // wave-uniform slow path: ties within the 2^16 bucket
    const unsigned tg = tf + 0x10000u;   // KEY_BIAS low16==0 -> bucket math unchanged
    const bool c0 = sel0 && (k0 < tg);
    const bool c1 = sel1 && (k1 < tg);
    const bool c2 = sel2 && (k2 < tg);
    const bool c3 = sel3 && (k3 < tg);
    const int nc = __popcll(__ballot(c0)) + __popcll(__ballot(c1))
                 + __popcll(__ballot(c2)) + __popcll(__ballot(c3));
    const int need2 = TOP_K - (cnt - nc);   // 1..8 to admit
    sel0 = sel0 && !c0; sel1 = sel1 && !c1;
    sel2 = sel2 && !c2; sel3 = sel3 && !c3;
    unsigned p0 = c0 ? (((k0 & 0xFFFFu) << 16) | (0xFFFFu - (unsigned)(ebase + 0))) : 0u;
    unsigned p1 = c1 ? (((k1 & 0xFFFFu) << 16) | (0xFFFFu - (unsigned)(ebase + 1))) : 0u;
    unsigned p2 = c2 ? (((k2 & 0xFFFFu) << 16) | (0xFFFFu - (unsigned)(ebase + 2))) : 0u;
    unsigned p3 = c3 ? (((k3 & 0xFFFFu) << 16) | (0xFFFFu - (unsigned)(ebase + 3))) : 0u;
    for (int r = 0; r < need2; ++r) {       // wave-uniform trips (exp. 1)
      unsigned mm = umax2(umax2(p0, p1), umax2(p2, p3));
      mm = umax2(mm, dpp_u32<DPP_XOR1>(mm));
      mm = umax2(mm, dpp_u32<DPP_XOR2>(mm));
      mm = umax2(mm, dpp_u32<DPP_HM>(mm));               // uniform within 8
      mm = umax2(mm, dpp_u32<DPP_M>(mm));                // uniform within 16
      mm = umax2(mm, (unsigned)__shfl_xor((int)mm, 16));
      mm = umax2(mm, (unsigned)__shfl_xor((int)mm, 32)); // wave-uniform
      const bool w0 = (p0 == mm), w1 = (p1 == mm), w2 = (p2 == mm), w3 = (p3 == mm);
      sel0 = sel0 || w0; sel1 = sel1 || w1;
      sel2 = sel2 || w2; sel3 = sel3 || w3;
      p0 = w0 ? 0u : p0; p1 = w1 ? 0u : p1;
      p2 = w2 ? 0u : p2; p3 = w3 ? 0u : p3;
    }
    sm0 = __ballot(sel0); sm1 = __ballot(sel1);
    sm2 = __ballot(sel2); sm3 = __ballot(sel3);
  }

  // ---- compact exactly-8 winners into LDS (slot = rank by expert idx) ----
  const int sbelow = mbcnt64(sm0) + mbcnt64(sm1) + mbcnt64(sm2) + mbcnt64(sm3);
  const int slot0 = sbelow;
  const int slot1 = slot0 + (int)sel0;
  const int slot2 = slot1 + (int)sel1;
  const int slot3 = slot2 + (int)sel2;

  float2* tb = buf[wid];
  if (sel0) tb[slot0] = make_float2(__int_as_float(ebase + 0), sig0);
  if (sel1) tb[slot1] = make_float2(__int_as_float(ebase + 1), sig1);
  if (sel2) tb[slot2] = make_float2(__int_as_float(ebase + 2), sig2);
  if (sel3) tb[slot3] = make_float2(__int_as_float(ebase + 3), sig3);
  asm volatile("s_waitcnt lgkmcnt(0)" ::: "memory");  // same-wave LDS RAW

  // ---- readback: own winner (l&7) AND partner winner (l>>3); 8-way broadcasts ----
  const int l8 = lane & 7;
  const float2 w  = tb[l8];
  const float2 wo = tb[lane >> 3];
  const float wsig = w.y;
  float ssum = wsig;
  ssum += dpp_f32<DPP_XOR1>(ssum);
  ssum += dpp_f32<DPP_XOR2>(ssum);
  ssum += dpp_f32<DPP_HM>(ssum);
  const float inv = __builtin_amdgcn_rcpf(ssum);   // <=1 ulp; ssum >= ~1e-3
  const float val = wsig * inv * ROUTED_SCALING;   // identical op order both uses
  const float v_o = wo.y * inv * ROUTED_SCALING;   // bit-identical to owner's val
  const float widx = (float)__float_as_int(w.x);
  const float i_o  = (float)__float_as_int(wo.x);

  // ---- final order via one pairwise ballot: winner a=(l&7) vs b=(l>>3) ----
  const unsigned long long rm =
      __ballot((val > v_o) || (val == v_o && widx < i_o));
  const int rank = __popc((unsigned)(rm >> (l8 << 3)) & 0xFFu);

  if (lane < TOP_K) {
    const int obase = token * TOP_K + rank;
    out_idx[obase] = widx;
    out_val[obase] = val;
  }
}

extern "C" void kernel_launch(void* const* d_in, const int* in_sizes, int n_in,
                              void* d_out, int out_size, void* d_ws, size_t ws_size,
                              hipStream_t stream) {
  const float* logits = (const float*)d_in[0];
  const float* bias   = (const float*)d_in[1];
  float* out = (float*)d_out;

  const int n_tokens = in_sizes[0] / 256;
  float* out_idx = out;
  float* out_val = out + (size_t)n_tokens * TOP_K;

  const int blocks = (n_tokens + 3) / 4;   // 4 waves (tokens) per 256-thread block
  moe_route_kernel<<<blocks, 256, 0, stream>>>(logits, bias, out_idx, out_val, n_tokens);
}